// Round 8
// baseline (272.726 us; speedup 1.0000x reference)
//
#include <hip/hip_runtime.h>
#include <hip/hip_bf16.h>

#define DEVFN static __device__ __forceinline__

typedef short bf16x8 __attribute__((ext_vector_type(8)));
typedef float f32x4  __attribute__((ext_vector_type(4)));

// ---------------- problem constants ----------------
constexpr int TSEQ  = 79;
constexpr int NSTEP = TSEQ + 7;    // 86 wavefront steps (even)
constexpr int MWG   = 16;          // batch rows per WAVE
constexpr int ROWU  = 344;         // LDS row stride in bf16 (172 dwords, %32==12 -> uniform banks)
constexpr int NBLK  = 16384 / 64;  // 256 blocks x 4 waves x 16 batch = 1 wave/SIMD

// per-layer tables. Unit map: x at unit 0; layer l h at [LO[l], LO[l]+LU[l]).
constexpr int LD[8]   = {1,64,32,16,8,16,32,64};        // input dim
constexpr int LU[8]   = {64,32,16,8,16,32,64,79};       // units
constexpr int LS[8]   = {0,8,72,104,120,128,144,176};   // input span start unit
constexpr int LO[8]   = {8,72,104,120,128,144,176,240}; // output start unit
constexpr int LKP[8]  = {96,96,64,32,32,64,96,160};     // K padded to 32
constexpr int LKS[8]  = {3,3,2,1,1,2,3,5};              // K-steps (KP/32)
constexpr int LUP[8]  = {64,32,16,16,16,32,64,80};      // padded rows in weight table
constexpr int WOFF[8] = {0,6144,9216,10240,10752,11264,13312,19456};
constexpr int WTOTAL  = 32256;                           // bf16 elems in weight table

// R17 design: INTRA-WAVE WAVEFRONT. One wave owns all 8 layers for its 16
// batch rows, but at step s layer l processes TIMESTEP s-l (R7's wavefront
// schedule folded into a single wave). Every layer's inputs — h_{l-1}(s-l)
// and its own h_l(s-l-1) — were both written at step s-1, so ALL reads come
// from the previous step's buffer (rb) and ALL writes go to wb:
//   * zero intra-step dependencies -> 63 MFMAs issue back-to-back
//   * no barriers, no fences: cross-step RAW (step s+1 reads wb(s)) is
//     guaranteed by same-wave in-order DS execution (R16 verified this)
//   * rb/wb are distinct named __shared__ arrays -> static no-alias
// History: R12-R14 fails were a bi[18] OOB (Sum(NT)=20) — fixed R15.
// R15 (full fences) 180.6us; R16 (no fences, serial layer chain) 154.2us,
// MfmaUtil 22.6 — serial chain + 1 wave/SIMD exposes every latency. R17
// removes the serial chain entirely.
constexpr int NT[8]  = {4,2,1,1,1,2,4,5};               // tiles per layer (sum 20)
constexpr int AO[8]  = {0,12,18,20,21,22,26,38};        // a-frag offsets (total 63)
constexpr int TO[8]  = {0,4,6,7,8,9,11,15};             // bias tile offsets (total 20)

DEVFN unsigned short f2bf(float f) {           // RNE (setup paths only)
  unsigned int u = __builtin_bit_cast(unsigned int, f);
  return (unsigned short)((u + 0x7FFFu + ((u >> 16) & 1u)) >> 16);
}
// hot-path pack: round-half-away (u+0x8000) + single v_perm_b32.
DEVFN unsigned int pk_rna(float a, float b) {
  unsigned int ua = __builtin_bit_cast(unsigned int, a) + 0x8000u;
  unsigned int ub = __builtin_bit_cast(unsigned int, b) + 0x8000u;
  return __builtin_amdgcn_perm(ub, ua, 0x07060302u);  // [ub.b3 ub.b2 ua.b3 ua.b2]
}
DEVFN float sigmoidf(float v) {
  return __builtin_amdgcn_rcpf(1.0f + __expf(-v));
}

// ---------------- weight prep: fp32 -> transposed, padded bf16 table in d_ws ----------------
__global__ void __launch_bounds__(256) prep_weights(
    const float* Wx0, const float* Wh0, const float* Wx1, const float* Wh1,
    const float* Wx2, const float* Wh2, const float* Wx3, const float* Wh3,
    const float* Wx4, const float* Wh4, const float* Wx5, const float* Wh5,
    const float* Wx6, const float* Wh6, const float* Wx7, const float* Wh7,
    unsigned short* __restrict__ wt)
{
  const float* wxp[8] = {Wx0,Wx1,Wx2,Wx3,Wx4,Wx5,Wx6,Wx7};
  const float* whp[8] = {Wh0,Wh1,Wh2,Wh3,Wh4,Wh5,Wh6,Wh7};
  int idx = blockIdx.x * 256 + threadIdx.x;
  if (idx >= WTOTAL) return;
#pragma unroll
  for (int l = 0; l < 8; ++l) {
    int sz = LUP[l] * LKP[l];
    if (idx >= WOFF[l] && idx < WOFF[l] + sz) {
      int local = idx - WOFF[l];
      int j = local / LKP[l];
      int k = local - j * LKP[l];
      float v = 0.f;
      if (j < LU[l]) {
        if (l == 0) {
          if (k == 0) v = Wx0[j];
          else if (k >= 8 && k < 72) v = Wh0[(k - 8) * 64 + j];
        } else {
          if (k < LD[l]) v = wxp[l][k * LU[l] + j];
          else if (k < LD[l] + LU[l]) v = whp[l][(k - LD[l]) * LU[l] + j];
        }
      }
      wt[idx] = f2bf(v);
    }
  }
}

// ---------------- per-wave preload: ALL layers' a-frags + bias frags ----------------
DEVFN void preload_all(const unsigned short* __restrict__ wt,
                       const float* const (&bptr)[8], int lane,
                       bf16x8 (&af)[63], f32x4 (&bi)[20])
{
  const int m0 = lane & 15, quad = lane >> 4;
#pragma unroll
  for (int l = 0; l < 8; ++l) {
#pragma unroll
    for (int t = 0; t < 5; ++t) {
      if (t >= NT[l]) continue;
      const unsigned short* base = wt + WOFF[l] + (t * 16 + m0) * LKP[l];
#pragma unroll
      for (int k = 0; k < 5; ++k) {
        if (k >= LKS[l]) continue;
        af[AO[l] + t * LKS[l] + k] =
            *reinterpret_cast<const bf16x8*>(base + k * 32 + quad * 8);
      }
      const float* bp = bptr[l];
      f32x4 bv;
#pragma unroll
      for (int r = 0; r < 4; ++r) {
        int j2 = t * 16 + quad * 4 + r;
        bv[r] = (j2 < LU[l]) ? bp[j2] : 0.0f;
      }
      bi[TO[l] + t] = bv;
    }
  }
}

// ---------------- one layer at wavefront step s (timestep s-L) ----------------
// reads rb only, writes wb only (rb != wb, distinct LDS objects).
template <int L, bool LAST>
DEVFN void layerW(int s, const unsigned short* rbase, unsigned short* wbase,
                  const bf16x8 (&af)[63], const f32x4 (&bi)[20],
                  float* __restrict__ out, int bb, int m, int quad)
{
  constexpr int ks = LKS[L], nt = NT[L], S = LS[L], O = LO[L], u = LU[L];
  if (s < L || s > L + TSEQ - 1) return;   // wave-uniform ramp guard
  f32x4 acc[5];
#pragma unroll
  for (int k = 0; k < 5; ++k) {
    if (k >= ks) continue;
    bf16x8 b = *reinterpret_cast<const bf16x8*>(rbase + S + k * 32);
#pragma unroll
    for (int t = 0; t < 5; ++t)
      if (t < nt)
        acc[t] = __builtin_amdgcn_mfma_f32_16x16x32_bf16(
            af[AO[L] + t * ks + k], b, (k == 0) ? bi[TO[L] + t] : acc[t], 0, 0, 0);
  }
  // epilogue: activation + RNA pack + one b64 LDS write per tile
#pragma unroll
  for (int t = 0; t < 5; ++t) {
    if (t >= nt) continue;
    const int jb = t * 16 + quad * 4;
    float v0 = acc[t][0], v1 = acc[t][1], v2 = acc[t][2], v3 = acc[t][3];
    if (L == 7) {
      v0 = sigmoidf(v0); v1 = sigmoidf(v1); v2 = sigmoidf(v2); v3 = sigmoidf(v3);
      if (LAST) {  // s == NSTEP-1 -> t==78: final h -> global output (fp32)
        float* op = out + (size_t)(bb + m) * 79 + jb;
        if (jb + 0 < 79) op[0] = v0;
        if (jb + 1 < 79) op[1] = v1;
        if (jb + 2 < 79) op[2] = v2;
        if (jb + 3 < 79) op[3] = v3;
      } else {
        uint2 pk;
        pk.x = pk_rna(v0, v1);
        pk.y = pk_rna(v2, v3);
        *reinterpret_cast<uint2*>(wbase + O + t * 16) = pk;  // j=79 -> pad unit 319 (zero weight)
      }
    } else {
      if (jb < u) {  // guards pad rows (l3 tile) from clobbering neighbor units
        v0 = fmaxf(v0, 0.f); v1 = fmaxf(v1, 0.f); v2 = fmaxf(v2, 0.f); v3 = fmaxf(v3, 0.f);
        uint2 pk;
        pk.x = pk_rna(v0, v1);
        pk.y = pk_rna(v2, v3);
        *reinterpret_cast<uint2*>(wbase + O + t * 16) = pk;
      }
    }
  }
}

// ---------------- one wavefront step: all 8 layers, zero intra-step deps ----------------
template <bool LAST>
DEVFN void stepW(int s, unsigned short (&rb)[MWG][ROWU], unsigned short (&wb)[MWG][ROWU],
                 const unsigned short (&xw)[MWG][80],
                 const bf16x8 (&af)[63], const f32x4 (&bi)[20],
                 float* __restrict__ out, int bb, int lane)
{
  const int m = lane & 15, quad = lane >> 4;
  // stage x_s into rb unit 0 (written before layer 0's read; in-order DS)
  if (lane < MWG && s < TSEQ) rb[lane][0] = xw[lane][s];
  const unsigned short* rbase = &rb[m][quad * 8];
  unsigned short* wbase = &wb[m][quad * 4];
  layerW<0, LAST>(s, rbase, wbase, af, bi, out, bb, m, quad);
  layerW<1, LAST>(s, rbase, wbase, af, bi, out, bb, m, quad);
  layerW<2, LAST>(s, rbase, wbase, af, bi, out, bb, m, quad);
  layerW<3, LAST>(s, rbase, wbase, af, bi, out, bb, m, quad);
  layerW<4, LAST>(s, rbase, wbase, af, bi, out, bb, m, quad);
  layerW<5, LAST>(s, rbase, wbase, af, bi, out, bb, m, quad);
  layerW<6, LAST>(s, rbase, wbase, af, bi, out, bb, m, quad);
  layerW<7, LAST>(s, rbase, wbase, af, bi, out, bb, m, quad);
}

// ---------------- main kernel: 4 independent waves per block, no barriers ----------------
__global__ void __launch_bounds__(256)
__attribute__((amdgpu_waves_per_eu(1, 1)))
rnn_reg(const float* __restrict__ x, const unsigned short* __restrict__ wt,
        const float* b0, const float* b1, const float* b2, const float* b3,
        const float* b4, const float* b5, const float* b6, const float* b7,
        float* __restrict__ out)
{
  __shared__ __align__(16) unsigned short hb0[4][MWG][ROWU];  // per-wave double-buffer
  __shared__ __align__(16) unsigned short hb1[4][MWG][ROWU];
  __shared__ __align__(4)  unsigned short xl[4][MWG][80];     // per-wave x rows, bf16
  const int tid = threadIdx.x, lane = tid & 63, wid = tid >> 6;
  const int bb = blockIdx.x * 64 + wid * MWG;
  const float* bptr[8] = {b0, b1, b2, b3, b4, b5, b6, b7};

  // zero both buffers (pad units must be 0; h(-1) = 0)
  {
    unsigned int* p0 = (unsigned int*)&hb0[0][0][0];
    unsigned int* p1 = (unsigned int*)&hb1[0][0][0];
    constexpr int NW = 4 * MWG * ROWU / 2;
    for (int i = tid; i < NW; i += 256) { p0[i] = 0; p1[i] = 0; }
  }
  // preload x: block's 64 rows are one contiguous span
  {
    const float* xb = x + (size_t)blockIdx.x * 64 * TSEQ;
    for (int i = tid; i < 64 * TSEQ; i += 256) {
      int r = i / TSEQ, c = i - r * TSEQ;
      xl[r >> 4][r & 15][c] = f2bf(xb[i]);
    }
  }
  bf16x8 af[63];
  f32x4  bi[20];
  preload_all(wt, bptr, lane, af, bi);
  __syncthreads();  // only barrier in the kernel: init handoff

  unsigned short (&hw0)[MWG][ROWU] = hb0[wid];
  unsigned short (&hw1)[MWG][ROWU] = hb1[wid];
  const unsigned short (&xw)[MWG][80] = xl[wid];

#pragma unroll 1
  for (int s = 0; s < NSTEP - 2; s += 2) {
    stepW<false>(s,     hw0, hw1, xw, af, bi, out, bb, lane);
    stepW<false>(s + 1, hw1, hw0, xw, af, bi, out, bb, lane);
  }
  stepW<false>(NSTEP - 2, hw0, hw1, xw, af, bi, out, bb, lane);
  stepW<true >(NSTEP - 1, hw1, hw0, xw, af, bi, out, bb, lane);
}

extern "C" void kernel_launch(void* const* d_in, const int* in_sizes, int n_in,
                              void* d_out, int out_size, void* d_ws, size_t ws_size,
                              hipStream_t stream)
{
  const float* x = (const float*)d_in[0];
  const float* Wx[8]; const float* Wh[8]; const float* b[8];
  for (int i = 0; i < 8; ++i) {
    Wx[i] = (const float*)d_in[1 + 3 * i];
    Wh[i] = (const float*)d_in[2 + 3 * i];
    b[i]  = (const float*)d_in[3 + 3 * i];
  }
  unsigned short* wt = (unsigned short*)d_ws;

  prep_weights<<<(WTOTAL + 255) / 256, 256, 0, stream>>>(
      Wx[0], Wh[0], Wx[1], Wh[1], Wx[2], Wh[2], Wx[3], Wh[3],
      Wx[4], Wh[4], Wx[5], Wh[5], Wx[6], Wh[6], Wx[7], Wh[7], wt);

  rnn_reg<<<NBLK, 256, 0, stream>>>(
      x, wt, b[0], b[1], b[2], b[3], b[4], b[5], b[6], b[7], (float*)d_out);
}